// Round 11
// baseline (163.836 us; speedup 1.0000x reference)
//
#include <hip/hip_runtime.h>

typedef float f32x4 __attribute__((ext_vector_type(4)));
typedef short short8 __attribute__((ext_vector_type(8)));
typedef unsigned int u32;
typedef unsigned short u16;
typedef u32 u32x2 __attribute__((ext_vector_type(2)));

#define CLL 0.25f                     // landmark self/neighbor coeff (deg=4)
#define CML 0.06019292654288460f      // 0.5/sqrt(69)
#define SELFM 0.014492753623188406f   // 1/69
#define UCS 208  // ucm col stride BYTES = 52 words = 4*13 (odd m) -> conflict-free b64 w / b128 r

__device__ __forceinline__ u16 f2bf(float x) {
  u32 b = __float_as_uint(x);
  return (u16)((b + 0x7FFFu + ((b >> 16) & 1u)) >> 16);
}
__device__ __forceinline__ u32 cvtpk(float a, float b) {
  u32 r;
  asm("v_cvt_pk_bf16_f32 %0, %1, %2" : "=v"(r) : "v"(a), "v"(b));
  return r;
}

// prep: (a) W frags with BN-scale FOLDED IN (W' = W*diag(sc), valid: sc>0);
//       (b) sc/sh table (sc still needed for layer 0, sh for epilogue);
//       (c) bias row table bb[l][c] = bias_l[c]*sc_l[c], pre-bf16;
//       (d) A_agg 12 frags (R7-proven) + bias column k=80 := 1.0.
__global__ void prep(const float* __restrict__ midW, const float* __restrict__ lastW,
                     const float* __restrict__ bng, const float* __restrict__ bnb,
                     const float* __restrict__ bnm, const float* __restrict__ bnv,
                     const float* __restrict__ cfb, const float* __restrict__ cmb,
                     const float* __restrict__ clb,
                     u16* __restrict__ frag, float* __restrict__ bns,
                     u16* __restrict__ afr, u16* __restrict__ bb) {
  const int t0 = blockIdx.x * blockDim.x + threadIdx.x;
  const int stride = gridDim.x * blockDim.x;
  // sc/sh table (bn index 0..6)
  for (int u = t0; u < 7 * 64; u += stride) {
    const int l = u >> 6, f = u & 63;
    const float sc = (float)((double)bng[l * 64 + f] / sqrt((double)bnv[l * 64 + f] + 1e-5));
    bns[l * 128 + f] = sc;
    bns[l * 128 + 64 + f] = bnb[l * 64 + f] - bnm[l * 64 + f] * sc;
  }
  // W fragments, scaled: frag lf (0..6) = layer lf+1; layers 1..6 use bn[lf+1], layer 7 none
  for (int u = t0; u < 7 * 4 * 2 * 64; u += stride) {
    const int lane = u & 63;
    const int t = u >> 6;
    const int ks = t & 1;
    const int nt = (t >> 1) & 3;
    const int lf = t >> 3;
    const float* W = (lf < 6) ? (midW + lf * 4096) : lastW;
    const int col = nt * 16 + (lane & 15);
    const int kb = ks * 32 + (lane >> 4) * 8;
    float scale = 1.f;
    if (lf < 6)
      scale = (float)((double)bng[(lf + 1) * 64 + col] /
                      sqrt((double)bnv[(lf + 1) * 64 + col] + 1e-5));
    u16* dst = frag + (size_t)u * 8;
#pragma unroll
    for (int j = 0; j < 8; ++j) dst[j] = f2bf(W[(kb + j) * 64 + col] * scale);
  }
  // bias rows (pre-bf16, scaled): l=0 cfb*sc0; 1..6 cmb*sc_l; 7 clb
  for (int u = t0; u < 8 * 64; u += stride) {
    const int l = u >> 6, c = u & 63;
    float b, s = 1.f;
    if (l == 0) {
      b = cfb[c];
      s = (float)((double)bng[c] / sqrt((double)bnv[c] + 1e-5));
    } else if (l <= 6) {
      b = cmb[(l - 1) * 64 + c];
      s = (float)((double)bng[l * 64 + c] / sqrt((double)bnv[l * 64 + c] + 1e-5));
    } else {
      b = clb[c];
    }
    bb[l * 64 + c] = f2bf(b * s);
  }
  // A_agg frags: p -> (mt, ks); F9 (mt1,ks2) reused for mt2. k=80 -> 1.0 bias col.
  const int MTs[12] = {0, 1, 2, 4, 1, 2, 3, 4, 0, 1, 3, 4};
  const int KSs[12] = {0, 0, 0, 0, 1, 1, 1, 1, 2, 2, 2, 2};
  for (int u = t0; u < 12 * 64; u += stride) {
    const int p = u >> 6, lane = u & 63;
    const int r = MTs[p] * 16 + (lane & 15);
    const int kb = KSs[p] * 32 + ((lane >> 4) << 3);
    u16* dst = afr + (size_t)u * 8;
#pragma unroll
    for (int j = 0; j < 8; ++j) {
      const int k = kb + j;
      float v = 0.f;
      if (r < 68) {
        if (k < 68) {
          if (k == r || k == (r + 1) % 68 || k == (r + 67) % 68) v = CLL;
        } else if (k == 68) v = CML;
        else if (k == 80) v = 1.f;
      } else if (r == 68) {
        if (k < 68) v = CML;
        else if (k == 68) v = SELFM;
        else if (k == 80) v = 1.f;
      }
      dst[j] = f2bf(v);
    }
  }
}

#define SUM4(V) ((V)[0] + (V)[1] + (V)[2] + (V)[3])
#define MAX4(V) fmaxf(fmaxf((V)[0], (V)[1]), fmaxf((V)[2], (V)[3]))
#define MM(A, B, C) __builtin_amdgcn_mfma_f32_16x16x32_bf16(A, B, C, 0, 0, 0)

// MFMA1: u = h @ W' for one M-tile, both N-tiles (shared A-frags)
#define MP3(HR, MT, TA, TB)                                            \
  {                                                                    \
    const short8 a0 = *(const short8*)&(HR)[(MT) * 1024 + ra0];        \
    const short8 a1 = *(const short8*)&(HR)[(MT) * 1024 + ra1];        \
    f32x4 accA = z4, accB = z4;                                        \
    accA = MM(a0, bA0, accA); accA = MM(a1, bA1, accA);                \
    accB = MM(a0, bB0, accB); accB = MM(a1, bB1, accB);                \
    TA = accA; TB = accB;                                              \
  }

// u -> ucm (col-major, linear, stride 208 B): one b64 per colset per mt
#define UW2(MT, TA, TB)                                                \
  {                                                                    \
    u32x2 wa, wb;                                                      \
    wa.x = cvtpk(TA[0], TA[1]); wa.y = cvtpk(TA[2], TA[3]);            \
    wb.x = cvtpk(TB[0], TB[1]); wb.y = cvtpk(TB[2], TB[3]);            \
    *(u32x2*)((char*)ucm + uwA + 32 * (MT)) = wa;                      \
    *(u32x2*)((char*)ucm + uwB + 32 * (MT)) = wb;                      \
  }

// MFMA2: ag = A_agg @ u for one colset (bias via k=80 column)
#define AGG5(URB, AG0, AG1, AG2, AG3, AG4)                             \
  {                                                                    \
    const short8 ub0 = *(const short8*)((const char*)ucm + (URB));       \
    const short8 ub1 = *(const short8*)((const char*)ucm + (URB) + 64);  \
    const short8 ub2 = *(const short8*)((const char*)ucm + (URB) + 128); \
    AG0 = MM(F8, ub2, MM(F0, ub0, z4));                                \
    AG1 = MM(F9, ub2, MM(F4, ub1, MM(F1, ub0, z4)));                   \
    AG2 = MM(F9, ub2, MM(F5, ub1, MM(F2, ub0, z4)));                   \
    AG3 = MM(F10, ub2, MM(F6, ub1, z4));                               \
    AG4 = MM(F11, ub2, MM(F7, ub1, MM(F3, ub0, z4)));                  \
  }

// epilogue: h = relu(ag) + sh (+ resid)   [bias & BN-scale already inside ag]
#define EPI4(AG, H, SH, RESID)                                         \
  {                                                                    \
    _Pragma("unroll") for (int e = 0; e < 4; ++e) {                    \
      float v = fmaxf(AG[e], 0.f) + (SH);                              \
      if (RESID) v += H[e];                                            \
      H[e] = v;                                                        \
    }                                                                  \
  }

// bf16 h write into swizzled hb for one col (4 scattered b16 stores)
#define WPAIR2(HW, MT, H, CQ)                                          \
  {                                                                    \
    const u32 pa = cvtpk(H[0], H[1]);                                  \
    const u32 pb = cvtpk(H[2], H[3]);                                  \
    (HW)[(16 * (MT) + 4 * qg + 0) * 64 + (CQ)] = (u16)pa;              \
    (HW)[(16 * (MT) + 4 * qg + 1) * 64 + ((CQ) ^ 8)] = (u16)(pa >> 16);\
    (HW)[(16 * (MT) + 4 * qg + 2) * 64 + ((CQ) ^ 16)] = (u16)pb;       \
    (HW)[(16 * (MT) + 4 * qg + 3) * 64 + ((CQ) ^ 24)] = (u16)(pb >> 16); \
  }

#define HWRITE(HW)                                                     \
  {                                                                    \
    u16* hw_ = (HW);                                                   \
    WPAIR2(hw_, 0, hA0, cqA) WPAIR2(hw_, 0, hB0, cqB)                  \
    WPAIR2(hw_, 1, hA1, cqA) WPAIR2(hw_, 1, hB1, cqB)                  \
    WPAIR2(hw_, 2, hA2, cqA) WPAIR2(hw_, 2, hB2, cqB)                  \
    WPAIR2(hw_, 3, hA3, cqA) WPAIR2(hw_, 3, hB3, cqB)                  \
    if (qg == 0) { WPAIR2(hw_, 4, hA4, cqA) WPAIR2(hw_, 4, hB4, cqB) } \
    else if (qg == 1) {                                                \
      hw_[68 * 64 + (cA ^ 32)] = (u16)cvtpk(hA4[0], hA4[0]);           \
      hw_[68 * 64 + (cB ^ 32)] = (u16)cvtpk(hB4[0], hB4[0]);           \
    }                                                                  \
  }

__launch_bounds__(128)
__global__ void gcn_fused(
    const float* __restrict__ x, const float* __restrict__ cfW,
    const float* __restrict__ aW1, const float* __restrict__ ab1,
    const float* __restrict__ aW2, const float* __restrict__ ab2,
    const float* __restrict__ f1W, const float* __restrict__ f1b,
    const float* __restrict__ f2W, const float* __restrict__ f2b,
    const u16* __restrict__ frag, const float* __restrict__ bns,
    const u16* __restrict__ afr, const u16* __restrict__ bb,
    float* __restrict__ out) {
  // LDS: 20480 + 13312 + 1280 + 256 + 768 + 512 = 36608 B -> 4 blocks/CU
  __shared__ u16 hb[2][80 * 64];            // bf16 h double-buffer (swizzled rows)
  __shared__ __align__(16) u16 ucm[64 * (UCS / 2)];  // u col-major [col][node 0..103], linear
  __shared__ float xl4[80 * 4];             // staged x, rows 69..79 = 0
  __shared__ float mrow[64];                // final master h
  __shared__ float gv[192];                 // readout concat [mean|max|master*att]
  __shared__ float part[128];               // cross-wave partials (att / fc1)

  const int tid = threadIdx.x;  // 0..127: 2 waves per graph
  const int g = blockIdx.x;
  const int lane = tid & 63;
  const int w = tid >> 6;
  const int p15 = lane & 15;
  const int qg = lane >> 4;
  const int cA = 32 * w + p15;
  const int cB = cA + 16;
  const f32x4 z4 = {0.f, 0.f, 0.f, 0.f};

  // MFMA1 A-frag read addrs (hb, XOR-swizzled; R10-proven conflict-free)
  const int rsw = (p15 & 7) << 3;
  const int ra0 = (p15 * 64 + qg * 8) ^ rsw;
  const int ra1 = (p15 * 64 + 32 + qg * 8) ^ rsw;
  // hb write swizzle bases
  const int cqA = cA ^ ((qg & 1) << 5);
  const int cqB = cqA ^ 16;
  // ucm addrs (linear; banks spread via odd-m stride 52 words)
  const int uwA = cA * UCS + 8 * qg;   // + 32*mt   (b64 writes)
  const int uwB = cB * UCS + 8 * qg;
  const int urA = cA * UCS + 16 * qg;  // + 64*ks   (b128 reads)
  const int urB = cB * UCS + 16 * qg;

  // A_agg constant fragments (12 x short8 = 48 VGPR)
  const u16* ap = afr + (size_t)lane * 8;
  const short8 F0 = *(const short8*)(ap);
  const short8 F1 = *(const short8*)(ap + 512);
  const short8 F2 = *(const short8*)(ap + 1024);
  const short8 F3 = *(const short8*)(ap + 1536);
  const short8 F4 = *(const short8*)(ap + 2048);
  const short8 F5 = *(const short8*)(ap + 2560);
  const short8 F6 = *(const short8*)(ap + 3072);
  const short8 F7 = *(const short8*)(ap + 3584);
  const short8 F8 = *(const short8*)(ap + 4096);
  const short8 F9 = *(const short8*)(ap + 4608);
  const short8 F10 = *(const short8*)(ap + 5120);
  const short8 F11 = *(const short8*)(ap + 5632);

  // prefetch layer-1 W' fragments
  const u16* f0p = frag + (((size_t)(2 * w) * 2) * 64 + lane) * 8;
  const u16* f1p = frag + (((size_t)(2 * w + 1) * 2) * 64 + lane) * 8;
  short8 bA0 = *(const short8*)f0p;
  short8 bA1 = *(const short8*)(f0p + 512);
  short8 bB0 = *(const short8*)f1p;
  short8 bB1 = *(const short8*)(f1p + 512);

  // zero hb pad rows (69..79, both buffers) + ucm pad nodes 80..103; stage x
  {
    u32* hz = (u32*)hb;
#pragma unroll
    for (int it = 0; it < 3; ++it) {
      const int i = tid + it * 128;
      if (i < 352) {
        hz[2208 + i] = 0u;
        hz[2560 + 2208 + i] = 0u;
      }
    }
    const int col = tid >> 1, half = tid & 1;
    *(f32x4*)((char*)ucm + col * UCS + 160 + 16 * half) = z4;  // nodes 80..95
    if (half == 0) *(f32x4*)((char*)ucm + col * UCS + 192) = z4;  // nodes 96..103
  }
  if (tid < 69)
    *(f32x4*)&xl4[tid * 4] = *(const f32x4*)&x[((size_t)g * 69 + tid) * 4];
  else if (tid < 80)
    *(f32x4*)&xl4[tid * 4] = z4;

  f32x4 tA0, tA1, tA2, tA3, tA4, tB0, tB1, tB2, tB3, tB4;
  f32x4 hA0, hA1, hA2, hA3, hA4, hB0, hB1, hB2, hB3, hB4;

  __syncthreads();

  // ---- layer 0: u = x @ (W_first*sc0) in fp32 -> ucm -> AGG -> h
  {
    const float sA = bns[cA], sB = bns[cB];
    const float wA0 = cfW[cA] * sA, wA1 = cfW[64 + cA] * sA;
    const float wA2 = cfW[128 + cA] * sA, wA3 = cfW[192 + cA] * sA;
    const float wB0 = cfW[cB] * sB, wB1 = cfW[64 + cB] * sB;
    const float wB2 = cfW[128 + cB] * sB, wB3 = cfW[192 + cB] * sB;
#define L0T(MT, TA, TB)                                                \
    { _Pragma("unroll") for (int r = 0; r < 4; ++r) {                  \
        const f32x4 xv = *(const f32x4*)&xl4[(16 * (MT) + 4 * qg + r) * 4]; \
        TA[r] = fmaf(xv[0], wA0, fmaf(xv[1], wA1, fmaf(xv[2], wA2, xv[3] * wA3))); \
        TB[r] = fmaf(xv[0], wB0, fmaf(xv[1], wB1, fmaf(xv[2], wB2, xv[3] * wB3))); } }
    L0T(0, tA0, tB0) L0T(1, tA1, tB1) L0T(2, tA2, tB2) L0T(3, tA3, tB3) L0T(4, tA4, tB4)
#undef L0T
    UW2(0, tA0, tB0) UW2(1, tA1, tB1) UW2(2, tA2, tB2) UW2(3, tA3, tB3) UW2(4, tA4, tB4)
    if (qg == 0) {  // bias row (node 80)
      ucm[cA * (UCS / 2) + 80] = bb[cA];
      ucm[cB * (UCS / 2) + 80] = bb[cB];
    }
    const float shA = bns[64 + cA], shB = bns[64 + cB];
    f32x4 gA0, gA1, gA2, gA3, gA4, gB0, gB1, gB2, gB3, gB4;
    AGG5(urA, gA0, gA1, gA2, gA3, gA4)
    AGG5(urB, gB0, gB1, gB2, gB3, gB4)
    EPI4(gA0, hA0, shA, false) EPI4(gA1, hA1, shA, false) EPI4(gA2, hA2, shA, false)
    EPI4(gA3, hA3, shA, false) EPI4(gA4, hA4, shA, false)
    EPI4(gB0, hB0, shB, false) EPI4(gB1, hB1, shB, false) EPI4(gB2, hB2, shB, false)
    EPI4(gB3, hB3, shB, false) EPI4(gB4, hB4, shB, false)
    HWRITE(&hb[0][0])
  }
  __syncthreads();

  // ---- layers 1..6: MFMA1 -> ucm -> MFMA2(A_agg, bias fused) -> relu+sh+resid
#pragma unroll 1
  for (int l = 1; l <= 6; ++l) {
    const u16* fA = frag + ((((size_t)l * 4 + 2 * w) * 2) * 64 + lane) * 8;
    const u16* fB = frag + ((((size_t)l * 4 + 2 * w + 1) * 2) * 64 + lane) * 8;
    const short8 nA0 = *(const short8*)fA;
    const short8 nA1 = *(const short8*)(fA + 512);
    const short8 nB0 = *(const short8*)fB;
    const short8 nB1 = *(const short8*)(fB + 512);
    const float shA = bns[l * 128 + 64 + cA], shB = bns[l * 128 + 64 + cB];
    const u16 brA = bb[l * 64 + cA], brB = bb[l * 64 + cB];
    const u16* hr = &hb[(l + 1) & 1][0];
    MP3(hr, 0, tA0, tB0) MP3(hr, 1, tA1, tB1) MP3(hr, 2, tA2, tB2)
    MP3(hr, 3, tA3, tB3) MP3(hr, 4, tA4, tB4)
    bA0 = nA0; bA1 = nA1; bB0 = nB0; bB1 = nB1;
    UW2(0, tA0, tB0) UW2(1, tA1, tB1) UW2(2, tA2, tB2) UW2(3, tA3, tB3) UW2(4, tA4, tB4)
    if (qg == 0) {
      ucm[cA * (UCS / 2) + 80] = brA;
      ucm[cB * (UCS / 2) + 80] = brB;
    }
    f32x4 gA0, gA1, gA2, gA3, gA4, gB0, gB1, gB2, gB3, gB4;
    AGG5(urA, gA0, gA1, gA2, gA3, gA4)
    AGG5(urB, gB0, gB1, gB2, gB3, gB4)
    EPI4(gA0, hA0, shA, true) EPI4(gA1, hA1, shA, true) EPI4(gA2, hA2, shA, true)
    EPI4(gA3, hA3, shA, true) EPI4(gA4, hA4, shA, true)
    EPI4(gB0, hB0, shB, true) EPI4(gB1, hB1, shB, true) EPI4(gB2, hB2, shB, true)
    EPI4(gB3, hB3, shB, true) EPI4(gB4, hB4, shB, true)
    HWRITE(&hb[l & 1][0])
    __syncthreads();
  }

  // ---- layer 7: MFMA1 -> ucm -> MFMA2 -> relu only (sh=0, no resid, no hb write)
  {
    const u16* hr = &hb[0][0];
    MP3(hr, 0, tA0, tB0) MP3(hr, 1, tA1, tB1) MP3(hr, 2, tA2, tB2)
    MP3(hr, 3, tA3, tB3) MP3(hr, 4, tA4, tB4)
    UW2(0, tA0, tB0) UW2(1, tA1, tB1) UW2(2, tA2, tB2) UW2(3, tA3, tB3) UW2(4, tA4, tB4)
    if (qg == 0) {
      ucm[cA * (UCS / 2) + 80] = bb[7 * 64 + cA];
      ucm[cB * (UCS / 2) + 80] = bb[7 * 64 + cB];
    }
    f32x4 gA0, gA1, gA2, gA3, gA4, gB0, gB1, gB2, gB3, gB4;
    AGG5(urA, gA0, gA1, gA2, gA3, gA4)
    AGG5(urB, gB0, gB1, gB2, gB3, gB4)
    EPI4(gA0, hA0, 0.f, false) EPI4(gA1, hA1, 0.f, false) EPI4(gA2, hA2, 0.f, false)
    EPI4(gA3, hA3, 0.f, false) EPI4(gA4, hA4, 0.f, false)
    EPI4(gB0, hB0, 0.f, false) EPI4(gB1, hB1, 0.f, false) EPI4(gB2, hB2, 0.f, false)
    EPI4(gB3, hB3, 0.f, false) EPI4(gB4, hB4, 0.f, false)
  }

  // ---- readout: per-col landmark mean/max from registers
  {
    float sA = SUM4(hA0) + SUM4(hA1) + SUM4(hA2) + SUM4(hA3);
    float sB = SUM4(hB0) + SUM4(hB1) + SUM4(hB2) + SUM4(hB3);
    float mA = fmaxf(fmaxf(MAX4(hA0), MAX4(hA1)), fmaxf(MAX4(hA2), MAX4(hA3)));
    float mB = fmaxf(fmaxf(MAX4(hB0), MAX4(hB1)), fmaxf(MAX4(hB2), MAX4(hB3)));
    if (qg == 0) {  // nodes 64..67 live in qg==0's mt=4 run
      sA += SUM4(hA4); mA = fmaxf(mA, MAX4(hA4));
      sB += SUM4(hB4); mB = fmaxf(mB, MAX4(hB4));
    }
    sA += __shfl_xor(sA, 16, 64); sA += __shfl_xor(sA, 32, 64);
    sB += __shfl_xor(sB, 16, 64); sB += __shfl_xor(sB, 32, 64);
    mA = fmaxf(mA, __shfl_xor(mA, 16, 64)); mA = fmaxf(mA, __shfl_xor(mA, 32, 64));
    mB = fmaxf(mB, __shfl_xor(mB, 16, 64)); mB = fmaxf(mB, __shfl_xor(mB, 32, 64));
    if (qg == 0) {
      gv[cA] = sA * (1.f / 68.f);
      gv[64 + cA] = mA;
      gv[cB] = sB * (1.f / 68.f);
      gv[64 + cB] = mB;
    }
    if (qg == 1) { mrow[cA] = hA4[0]; mrow[cB] = hB4[0]; }  // node 68
  }
  __syncthreads();

  // ---- attention gate (k-split across the 2 waves)
  {
    const int f = tid & 63;
    const int kh = tid >> 6;
    float z = 0.f;
#pragma unroll
    for (int k = 0; k < 32; ++k)
      z = fmaf(mrow[kh * 32 + k], aW1[(kh * 32 + k) * 64 + f], z);
    part[tid] = z;
  }
  __syncthreads();
  if (tid < 64) {
    float z = part[tid] + part[64 + tid] + ab1[tid];
    z = fmaxf(z, 0.f);
    float pr = z * aW2[tid];
#pragma unroll
    for (int off = 32; off > 0; off >>= 1) pr += __shfl_xor(pr, off, 64);
    const float att = 1.f / (1.f + expf(-(pr + ab2[0])));
    gv[128 + tid] = mrow[tid] * att;
  }
  __syncthreads();

  // ---- fc1 partials (i-split across the 2 waves)
  {
    const int f = tid & 63;
    const int ih = tid >> 6;
    float a = 0.f;
#pragma unroll
    for (int i = 0; i < 96; ++i)
      a = fmaf(gv[ih * 96 + i], f1W[(ih * 96 + i) * 64 + f], a);
    part[tid] = a;
  }
  __syncthreads();
  if (tid < 64) {
    float a = part[tid] + part[64 + tid] + f1b[tid];
    const float y = fmaxf(a, 0.f);
    float po[7];
#pragma unroll
    for (int o = 0; o < 7; ++o) po[o] = y * f2W[tid * 7 + o];
#pragma unroll
    for (int o = 0; o < 7; ++o)
#pragma unroll
      for (int off = 32; off > 0; off >>= 1) po[o] += __shfl_xor(po[o], off, 64);
    if (tid == 0) {
#pragma unroll
      for (int o = 0; o < 7; ++o) out[(size_t)g * 7 + o] = po[o] + f2b[o];
    }
  }
}

extern "C" void kernel_launch(void* const* d_in, const int* in_sizes, int n_in,
                              void* d_out, int out_size, void* d_ws, size_t ws_size,
                              hipStream_t stream) {
  (void)in_sizes; (void)n_in; (void)ws_size;
  const float* x   = (const float*)d_in[0];
  const float* cfW = (const float*)d_in[4];
  const float* cfb = (const float*)d_in[5];
  const float* cmW = (const float*)d_in[6];
  const float* cmb = (const float*)d_in[7];
  const float* clW = (const float*)d_in[8];
  const float* clb = (const float*)d_in[9];
  const float* bng = (const float*)d_in[10];
  const float* bnb = (const float*)d_in[11];
  const float* bnm = (const float*)d_in[12];
  const float* bnv = (const float*)d_in[13];
  const float* aW1 = (const float*)d_in[14];
  const float* ab1 = (const float*)d_in[15];
  const float* aW2 = (const float*)d_in[16];
  const float* ab2 = (const float*)d_in[17];
  const float* f1W = (const float*)d_in[18];
  const float* f1b = (const float*)d_in[19];
  const float* f2W = (const float*)d_in[20];
  const float* f2b = (const float*)d_in[21];

  u16* frag  = (u16*)d_ws;                           // 57344 B (W' frags, sc-folded)
  float* bns = (float*)((char*)d_ws + 57344);        // 3584 B (sc/sh)
  u16* afr   = (u16*)((char*)d_ws + 60928);          // 12288 B (A_agg frags)
  u16* bb    = (u16*)((char*)d_ws + 73216);          // 1024 B (scaled bias rows, bf16)
  const int ngraphs = out_size / 7;

  prep<<<dim3(16), dim3(256), 0, stream>>>(cmW, clW, bng, bnb, bnm, bnv,
                                           cfb, cmb, clb, frag, bns, afr, bb);
  gcn_fused<<<dim3(ngraphs), dim3(128), 0, stream>>>(
      x, cfW, aW1, ab1, aW2, ab2, f1W, f1b, f2W, f2b,
      frag, bns, afr, bb, (float*)d_out);
}